// Round 8
// baseline (281.480 us; speedup 1.0000x reference)
//
#include <hip/hip_runtime.h>
#include <math.h>

// Problem constants (from reference): N=65536 rows, D=512 features, K=5 centroids.
#define LFR_N 65536
#define LFR_D 512
#define LFR_K 5
#define RPW   8                      // rows per wave (8 lanes per row)
#define WPB   4                      // waves per block
#define BLOCKS (LFR_N / (RPW * WPB * 8) * 8)   // 2048
#define NF4   (LFR_D / 4 / 8)        // 16 float4 steps per thread

// R8: COPY-SHAPED KERNEL (thread-autonomous dense streaming).
// R0-R7: seven structures, two load-return paths, stream split - all pinned
// at 80-88us / ~2.4 TB/s with every pipe idle. But m13 (float4 copy, THIS
// chip) does 6.29 TB/s read+write - so "reads cap at 2.4" is not platform
// truth. The copy differs from all seven: thread-autonomous unbroken
// load/store streams, no cross-lane ops in the data path, no phases, no
// LDS round-trip, waves never stop issuing. This kernel replicates that
// shape: lane=(row*8+q); q owns f4s q,q+8,..; every wave-load = 8 fully-
// covered 128B lines (copy-identical); dist accumulates per-thread in
// registers DIRECTLY off the loads; constants via conflict-free LDS
// broadcast (8 distinct addrs/inst, banks 0..31 exactly); one 15-shuffle
// reduce + redundant softmax at the end; rec regenerated per-thread,
// full-line streaming stores. 2048 blocks = 8/CU, launch_bounds(256,8)
// -> 32 waves/CU (2x any prior round), unroll 4 = 4 indep loads in
// flight per THREAD continuously.
__global__ __launch_bounds__(256, 8) void lfr_kernel(
    const float* __restrict__ x,        // (N, D)
    const float* __restrict__ alpha,    // (D,)
    const float* __restrict__ w,        // (K, 1)
    const float* __restrict__ cent,     // (K, D)
    float* __restrict__ out_map,        // (N, K)
    float* __restrict__ out_rec,        // (N, D)
    float* __restrict__ out_pred)       // (N,)
{
    __shared__ float sc[LFR_K][LFR_D];   // 10 KB centroids
    __shared__ float sa2[LFR_D];         //  2 KB  (-2*alpha)
    __shared__ float scp[LFR_K][8];      // cst partials
    __shared__ float scst[LFR_K];        // sum_d alpha*c_k^2
    __shared__ float ssig[LFR_K];        // sigmoid(w)

    const int tid  = threadIdx.x;
    const int lane = tid & 63;
    const int wib  = tid >> 6;
    const int wid  = blockIdx.x * WPB + wib;
    const int rq   = lane >> 3;          // row within wave
    const int q    = lane & 7;           // d-phase (f4s q, q+8, ...)

    // ---- stage centroids + (-2*alpha) cooperatively ----
    {
        const float4* csrc = (const float4*)cent;         // 640 float4
        float4* cdst = (float4*)&sc[0][0];
        #pragma unroll
        for (int i = 0; i < 3; ++i) {
            int idx = tid + i * 256;
            if (idx < (LFR_K * LFR_D) / 4) cdst[idx] = csrc[idx];
        }
        if (tid < LFR_D / 4) {
            float4 a = ((const float4*)alpha)[tid];
            a.x *= -2.0f; a.y *= -2.0f; a.z *= -2.0f; a.w *= -2.0f;
            ((float4*)sa2)[tid] = a;
        }
    }
    __syncthreads();
    // cst partials: 40 threads, each sums 64 d's of one k. cst = -0.5*sum(sa2*c^2).
    if (tid < LFR_K * 8) {
        const int k = tid >> 3, part = tid & 7;
        float s = 0.0f;
        for (int j = part * 64; j < part * 64 + 64; ++j) {
            float cc = sc[k][j];
            s = fmaf(sa2[j] * cc, cc, s);
        }
        scp[k][part] = s;
    }
    __syncthreads();
    if (tid < LFR_K) {
        float s = 0.0f;
        #pragma unroll
        for (int p = 0; p < 8; ++p) s += scp[tid][p];
        scst[tid] = -0.5f * s;
        ssig[tid] = 1.0f / (1.0f + __expf(-w[tid]));
    }
    __syncthreads();   // last barrier in the kernel

    // ---- this thread's row and d-stream ----
    const size_t row = (size_t)wid * RPW + rq;
    const float* xr = x + row * LFR_D + q * 4;

    // ---- pass 1: dense streaming dist accumulation (thread-autonomous) ----
    float dacc[LFR_K] = {0.f, 0.f, 0.f, 0.f, 0.f};
    #pragma unroll 4
    for (int j = 0; j < NF4; ++j) {
        float4 xv = *(const float4*)(xr + j * 32);       // 8 full lines / wave-inst
        const int dof = j * 32 + q * 4;
        float4 av = *(const float4*)&sa2[dof];           // LDS broadcast, bank-exact
        float v0 = av.x * xv.x, v1 = av.y * xv.y;
        float v2 = av.z * xv.z, v3 = av.w * xv.w;
        #pragma unroll
        for (int k = 0; k < LFR_K; ++k) {
            float4 cv = *(const float4*)&sc[k][dof];
            dacc[k] = fmaf(cv.x, v0, dacc[k]);
            dacc[k] = fmaf(cv.y, v1, dacc[k]);
            dacc[k] = fmaf(cv.z, v2, dacc[k]);
            dacc[k] = fmaf(cv.w, v3, dacc[k]);
        }
    }

    // ---- end-only reduce across the row's 8 lanes (xor 1,2,4) ----
    #pragma unroll
    for (int k = 0; k < LFR_K; ++k) {
        dacc[k] += __shfl_xor(dacc[k], 1);
        dacc[k] += __shfl_xor(dacc[k], 2);
        dacc[k] += __shfl_xor(dacc[k], 4);
        dacc[k] += scst[k];              // add the row-shifted constant once
    }

    // ---- softmax per lane (redundant x8 per row - no exchange needed) ----
    float e[LFR_K];
    float mx = dacc[0];
    #pragma unroll
    for (int k = 1; k < LFR_K; ++k) mx = fmaxf(mx, dacc[k]);
    float sum = 0.f;
    #pragma unroll
    for (int k = 0; k < LFR_K; ++k) { e[k] = __expf(dacc[k] - mx); sum += e[k]; }
    float inv = 1.0f / sum;
    #pragma unroll
    for (int k = 0; k < LFR_K; ++k) e[k] *= inv;

    // ---- map + pred (q==0 lane of each row; 8 rows x 20B contiguous/wave) ----
    if (q == 0) {
        float* mp = out_map + row * LFR_K;
        *(float4*)(mp) = make_float4(e[0], e[1], e[2], e[3]);
        mp[4] = e[4];
        float pr = e[0] * ssig[0];
        #pragma unroll
        for (int k = 1; k < LFR_K; ++k) pr = fmaf(e[k], ssig[k], pr);
        out_pred[row] = pr;
    }

    // ---- pass 2: regenerate rec, dense streaming stores (full lines) ----
    float* rr = out_rec + row * LFR_D + q * 4;
    #pragma unroll 4
    for (int j = 0; j < NF4; ++j) {
        const int dof = j * 32 + q * 4;
        float4 c0 = *(const float4*)&sc[0][dof];
        float4 rv;
        rv.x = e[0] * c0.x; rv.y = e[0] * c0.y;
        rv.z = e[0] * c0.z; rv.w = e[0] * c0.w;
        #pragma unroll
        for (int k = 1; k < LFR_K; ++k) {
            float4 cv = *(const float4*)&sc[k][dof];
            rv.x = fmaf(e[k], cv.x, rv.x);
            rv.y = fmaf(e[k], cv.y, rv.y);
            rv.z = fmaf(e[k], cv.z, rv.z);
            rv.w = fmaf(e[k], cv.w, rv.w);
        }
        *(float4*)(rr + j * 32) = rv;
    }
}

extern "C" void kernel_launch(void* const* d_in, const int* in_sizes, int n_in,
                              void* d_out, int out_size, void* d_ws, size_t ws_size,
                              hipStream_t stream) {
    const float* x     = (const float*)d_in[0];   // (N, D)
    // d_in[1] = is_protected — unused by the reference computation
    const float* alpha = (const float*)d_in[2];   // (D,)
    const float* w     = (const float*)d_in[3];   // (K, 1)
    const float* cent  = (const float*)d_in[4];   // (K, D)

    float* out   = (float*)d_out;
    float* o_map = out;                                         // N*K
    float* o_rec = out + (size_t)LFR_N * LFR_K;                 // N*D
    float* o_prd = out + (size_t)LFR_N * LFR_K + (size_t)LFR_N * LFR_D;  // N

    // 2048 blocks x 256 threads = 8 blocks/CU; launch_bounds(256,8) targets
    // 32 waves/CU. Each wave: 8 rows, copy-shaped autonomous streams.
    dim3 grid(BLOCKS), block(256);
    lfr_kernel<<<grid, block, 0, stream>>>(x, alpha, w, cent, o_map, o_rec, o_prd);
}